// Round 1
// baseline (5346.856 us; speedup 1.0000x reference)
//
#include <hip/hip_runtime.h>

#define EPS 1e-6f

__device__ inline unsigned int fkey(float f) {
  unsigned int u = __float_as_uint(f);
  return (u & 0x80000000u) ? ~u : (u | 0x80000000u);
}

__device__ inline unsigned long long shfl_xor_u64(unsigned long long v, int mask) {
  unsigned int lo = (unsigned int)(v & 0xffffffffull);
  unsigned int hi = (unsigned int)(v >> 32);
  lo = (unsigned int)__shfl_xor((int)lo, mask);
  hi = (unsigned int)__shfl_xor((int)hi, mask);
  return (((unsigned long long)hi) << 32) | lo;
}

// ---------------- codebook squared norms: one wave per code row ----------------
__global__ __launch_bounds__(256) void cbsq_kernel(const float* __restrict__ cb,
                                                   float* __restrict__ cbsq) {
  int row = blockIdx.x * 4 + (threadIdx.x >> 6);
  int lane = threadIdx.x & 63;
  const float4* p = (const float4*)(cb + (size_t)row * 512);
  float4 v0 = p[lane];
  float4 v1 = p[lane + 64];
  float s = v0.x*v0.x + v0.y*v0.y + v0.z*v0.z + v0.w*v0.w
          + v1.x*v1.x + v1.y*v1.y + v1.z*v1.z + v1.w*v1.w;
  #pragma unroll
  for (int off = 32; off; off >>= 1) s += __shfl_xor(s, off);
  if (lane == 0) cbsq[row] = s;
}

// ---------------- fused distance GEMM + argmin ----------------
// Block: 256 threads. Tile: 64 rows x 64 codes, loop over all 16 code tiles,
// K tiled by 32. Running per-row argmin kept as packed (ordered_d2, index) u64.
#define TM 64
#define TN 64
#define TK 32
#define LPAD 4  // row length TM+4 = 68 floats, keeps float4 alignment

__global__ __launch_bounds__(256) void argmin_kernel(
    const float* __restrict__ R,     // [32768, 512] residual
    const float* __restrict__ CB,    // [1024, 512] this stage's codebook
    const float* __restrict__ cbsq,  // [1024]
    int* __restrict__ ind,           // [32768]
    float* __restrict__ ind_f,       // d_out indices region, row-stride 8
    int qi) {
  __shared__ float As[TK][TM + LPAD];
  __shared__ float Bs[TK][TN + LPAD];
  const int tid = threadIdx.x;
  const int tx = tid & 15;   // code direction (16 x 4 codes)
  const int ty = tid >> 4;   // row direction  (16 x 4 rows)
  const int row0 = blockIdx.x * TM;

  unsigned long long best[4];
  #pragma unroll
  for (int i = 0; i < 4; i++) best[i] = ~0ull;

  for (int ct = 0; ct < 1024 / TN; ct++) {
    const int c0 = ct * TN;
    float acc[4][4];
    #pragma unroll
    for (int i = 0; i < 4; i++)
      #pragma unroll
      for (int j = 0; j < 4; j++) acc[i][j] = 0.f;

    for (int kt = 0; kt < 512 / TK; kt++) {
      const int ko = kt * TK;
      // stage A (rows) and B (codes) tiles, transposed into [k][m] layout
      #pragma unroll
      for (int it = 0; it < 2; it++) {
        int idx = it * 256 + tid;
        int r  = idx >> 3;          // 0..63
        int kq = (idx & 7) << 2;    // 0,4,...,28
        float4 v = *(const float4*)(R  + (size_t)(row0 + r) * 512 + ko + kq);
        As[kq + 0][r] = v.x; As[kq + 1][r] = v.y;
        As[kq + 2][r] = v.z; As[kq + 3][r] = v.w;
        float4 w = *(const float4*)(CB + (size_t)(c0 + r) * 512 + ko + kq);
        Bs[kq + 0][r] = w.x; Bs[kq + 1][r] = w.y;
        Bs[kq + 2][r] = w.z; Bs[kq + 3][r] = w.w;
      }
      __syncthreads();
      #pragma unroll
      for (int k = 0; k < TK; k++) {
        float4 a4 = *(const float4*)&As[k][ty * 4];
        float4 b4 = *(const float4*)&Bs[k][tx * 4];
        float av[4] = {a4.x, a4.y, a4.z, a4.w};
        float bv[4] = {b4.x, b4.y, b4.z, b4.w};
        #pragma unroll
        for (int i = 0; i < 4; i++)
          #pragma unroll
          for (int j = 0; j < 4; j++)
            acc[i][j] = fmaf(av[i], bv[j], acc[i][j]);
      }
      __syncthreads();
    }

    // d2 = cbsq[c] - 2*dot ; per-row min across this 64-code tile
    #pragma unroll
    for (int i = 0; i < 4; i++) {
      unsigned long long m = ~0ull;
      #pragma unroll
      for (int j = 0; j < 4; j++) {
        int c = c0 + tx * 4 + j;
        float d2 = fmaf(-2.f, acc[i][j], cbsq[c]);
        unsigned long long p =
            (((unsigned long long)fkey(d2)) << 32) | (unsigned int)c;
        if (p < m) m = p;
      }
      // reduce across the 16 tx lanes (lane bits 0..3, same wave)
      #pragma unroll
      for (int off = 1; off < 16; off <<= 1) {
        unsigned long long o = shfl_xor_u64(m, off);
        if (o < m) m = o;
      }
      if (m < best[i]) best[i] = m;
    }
  }

  if (tx == 0) {
    #pragma unroll
    for (int i = 0; i < 4; i++) {
      int r = row0 + ty * 4 + i;
      int c = (int)(best[i] & 0xffffffffu);
      ind[r] = c;
      ind_f[(size_t)r * 8 + qi] = (float)c;
    }
  }
}

// ---------------- rotation trick + residual update: one wave per row ----------------
__global__ __launch_bounds__(256) void rotate_kernel(
    float* __restrict__ R, const float* __restrict__ CB,
    const int* __restrict__ ind, float* __restrict__ loss_out,
    float inv_total, int qi) {
  int wave = threadIdx.x >> 6;
  int lane = threadIdx.x & 63;
  int row = blockIdx.x * 4 + wave;
  float4* zr = (float4*)(R + (size_t)row * 512);
  const float4* qr = (const float4*)(CB + (size_t)ind[row] * 512);
  float4 z0 = zr[lane], z1 = zr[lane + 64];
  float4 q0 = qr[lane], q1 = qr[lane + 64];

  float zz = z0.x*z0.x + z0.y*z0.y + z0.z*z0.z + z0.w*z0.w
           + z1.x*z1.x + z1.y*z1.y + z1.z*z1.z + z1.w*z1.w;
  float qq = q0.x*q0.x + q0.y*q0.y + q0.z*q0.z + q0.w*q0.w
           + q1.x*q1.x + q1.y*q1.y + q1.z*q1.z + q1.w*q1.w;
  float zq = z0.x*q0.x + z0.y*q0.y + z0.z*q0.z + z0.w*q0.w
           + z1.x*q1.x + z1.y*q1.y + z1.z*q1.z + z1.w*q1.w;
  #pragma unroll
  for (int off = 32; off; off >>= 1) {
    zz += __shfl_xor(zz, off);
    qq += __shfl_xor(qq, off);
    zq += __shfl_xor(zq, off);
  }

  float nz = sqrtf(zz), nq = sqrtf(qq);
  float inz = 1.f / (nz + EPS), inq = 1.f / (nq + EPS);
  float ns  = sqrtf(zz*inz*inz + 2.f*zq*inz*inq + qq*inq*inq);
  float ins = 1.f / ns;
  float zw  = (zz*inz + zq*inq) * ins;   // z . w
  float zzn = zz * inz;                  // z . z_norm
  float scale = nq * inz;                // ||q|| / (||z||+eps)
  // e = z*(1 - 2*zw*ins*inz) + q*inq*(2*zzn - 2*zw*ins); quant = scale*e
  float az = scale * (1.f - 2.f * zw * ins * inz);
  float aq = scale * (2.f * zzn - 2.f * zw * ins) * inq;

  float4 r0, r1;
  r0.x = z0.x - (az*z0.x + aq*q0.x);
  r0.y = z0.y - (az*z0.y + aq*q0.y);
  r0.z = z0.z - (az*z0.z + aq*q0.z);
  r0.w = z0.w - (az*z0.w + aq*q0.w);
  r1.x = z1.x - (az*z1.x + aq*q1.x);
  r1.y = z1.y - (az*z1.y + aq*q1.y);
  r1.z = z1.z - (az*z1.z + aq*q1.z);
  r1.w = z1.w - (az*z1.w + aq*q1.w);
  zr[lane] = r0;
  zr[lane + 64] = r1;

  // commitment loss: mean over all M*D elements of (q - z)^2 = (qq - 2 zq + zz)/total
  __shared__ float ls[4];
  if (lane == 0) ls[wave] = (zz - 2.f*zq + qq);
  __syncthreads();
  if (threadIdx.x == 0)
    atomicAdd(loss_out + qi, (ls[0] + ls[1] + ls[2] + ls[3]) * inv_total);
}

// ---------------- quantized_out = x - residual_final ----------------
__global__ __launch_bounds__(256) void finish_kernel(const float4* __restrict__ x,
                                                     const float4* __restrict__ r,
                                                     float4* __restrict__ qout) {
  size_t i = (size_t)blockIdx.x * 256 + threadIdx.x;
  float4 a = x[i], b = r[i];
  float4 o;
  o.x = a.x - b.x; o.y = a.y - b.y; o.z = a.z - b.z; o.w = a.w - b.w;
  qout[i] = o;
}

extern "C" void kernel_launch(void* const* d_in, const int* in_sizes, int n_in,
                              void* d_out, int out_size, void* d_ws, size_t ws_size,
                              hipStream_t stream) {
  const float* x   = (const float*)d_in[0];   // [16, 2048, 512]
  const float* cbs = (const float*)d_in[1];   // [8, 1024, 512]
  float* out = (float*)d_out;
  const size_t M = 32768, D = 512, Q = 8, C = 1024;
  float* qout     = out;                 // [M, D]
  float* idx_out  = out + M * D;         // [M, Q] (as float)
  float* loss_out = idx_out + M * Q;     // [Q]

  // workspace layout: residual [M*D] | cbsq [Q*C] | ind [M]
  float* resid = (float*)d_ws;
  float* cbsq  = resid + M * D;
  int*   ind   = (int*)(cbsq + Q * C);

  hipMemsetAsync(loss_out, 0, Q * sizeof(float), stream);
  hipMemcpyAsync(resid, x, M * D * sizeof(float), hipMemcpyDeviceToDevice, stream);
  cbsq_kernel<<<(int)((Q * C) / 4), 256, 0, stream>>>(cbs, cbsq);

  const float inv_total = 1.f / (float)(M * D);
  for (int qi = 0; qi < (int)Q; qi++) {
    const float* cb = cbs + (size_t)qi * C * D;
    argmin_kernel<<<(int)(M / TM), 256, 0, stream>>>(resid, cb, cbsq + qi * C,
                                                     ind, idx_out, qi);
    rotate_kernel<<<(int)(M / 4), 256, 0, stream>>>(resid, cb, ind, loss_out,
                                                    inv_total, qi);
  }
  finish_kernel<<<(int)((M * D / 4) / 256), 256, 0, stream>>>(
      (const float4*)x, (const float4*)resid, (float4*)qout);
}

// Round 2
// 2350.726 us; speedup vs baseline: 2.2746x; 2.2746x over previous
//
#include <hip/hip_runtime.h>

#define EPS 1e-6f

typedef __attribute__((ext_vector_type(8))) short bf16x8;
typedef __attribute__((ext_vector_type(4))) float f32x4;
typedef __attribute__((ext_vector_type(8))) unsigned short ushort8;

#define AS1(p) ((const __attribute__((address_space(1))) void*)(p))
#define AS3(p) ((__attribute__((address_space(3))) void*)(p))

__device__ inline unsigned int fkey(float f) {
  unsigned int u = __float_as_uint(f);
  return (u & 0x80000000u) ? ~u : (u | 0x80000000u);
}

__device__ inline unsigned long long shfl_xor_u64(unsigned long long v, int mask) {
  unsigned int lo = (unsigned int)(v & 0xffffffffull);
  unsigned int hi = (unsigned int)(v >> 32);
  lo = (unsigned int)__shfl_xor((int)lo, mask);
  hi = (unsigned int)__shfl_xor((int)hi, mask);
  return (((unsigned long long)hi) << 32) | lo;
}

__device__ inline unsigned short f2bf(float f) {  // RNE fp32 -> bf16
  unsigned int u = __float_as_uint(f);
  u += 0x7fffu + ((u >> 16) & 1u);
  return (unsigned short)(u >> 16);
}
__device__ inline float bf2f(unsigned short h) {
  return __uint_as_float(((unsigned int)h) << 16);
}

// ---------------- codebook squared norms: one wave per code row (8192 rows) ----------------
__global__ __launch_bounds__(256) void cbsq_kernel(const float* __restrict__ cb,
                                                   float* __restrict__ cbsq) {
  int row = blockIdx.x * 4 + (threadIdx.x >> 6);
  int lane = threadIdx.x & 63;
  const float4* p = (const float4*)(cb + (size_t)row * 512);
  float4 v0 = p[lane];
  float4 v1 = p[lane + 64];
  float s = v0.x*v0.x + v0.y*v0.y + v0.z*v0.z + v0.w*v0.w
          + v1.x*v1.x + v1.y*v1.y + v1.z*v1.z + v1.w*v1.w;
  #pragma unroll
  for (int off = 32; off; off >>= 1) s += __shfl_xor(s, off);
  if (lane == 0) cbsq[row] = s;
}

// ---------------- fp32 -> (hi, lo) bf16 split, 8 elems/thread ----------------
__global__ __launch_bounds__(256) void split_kernel(const float* __restrict__ src,
                                                    unsigned short* __restrict__ hi,
                                                    unsigned short* __restrict__ lo) {
  size_t i = ((size_t)blockIdx.x * 256 + threadIdx.x) * 8;
  float4 v0 = *(const float4*)(src + i);
  float4 v1 = *(const float4*)(src + i + 4);
  float v[8] = {v0.x, v0.y, v0.z, v0.w, v1.x, v1.y, v1.z, v1.w};
  ushort8 h, l;
  #pragma unroll
  for (int j = 0; j < 8; j++) {
    unsigned short hh = f2bf(v[j]);
    h[j] = hh;
    l[j] = f2bf(v[j] - bf2f(hh));
  }
  *(ushort8*)(hi + i) = h;
  *(ushort8*)(lo + i) = l;
}

// ---------------- MFMA distance GEMM + per-block argmin partials ----------------
// 128 rows x 128 codes per block, 4 waves (2x2), K_phys = 3 x 512 (hi*hi, hi*lo, lo*hi).
// partial[row][cb*2 + wc] = packed (ordered_d2, col) u64 min over the wave's 64 codes.
__global__ __launch_bounds__(256) void argmin_mfma(
    const unsigned short* __restrict__ Rhi, const unsigned short* __restrict__ Rlo,
    const unsigned short* __restrict__ Chi, const unsigned short* __restrict__ Clo,
    const float* __restrict__ cbsq, unsigned long long* __restrict__ partial) {
  __shared__ unsigned short As[128 * 32];
  __shared__ unsigned short Bs[128 * 32];
  const int tid = threadIdx.x;
  const int lane = tid & 63;
  const int w = tid >> 6;
  const int wr = w >> 1, wc = w & 1;
  const int cb = blockIdx.x;   // 0..7   (fastest: codebook stays L2-hot per row tile)
  const int rb = blockIdx.y;   // 0..255
  const int row0 = rb * 128;
  const int col0 = cb * 128;

  const int srow = lane >> 2;        // 0..15: row within 16-row staging chunk
  const int skq  = (lane & 3) * 8;   // element offset within 32-elem row

  f32x4 acc[4][4];
  #pragma unroll
  for (int mi = 0; mi < 4; mi++)
    #pragma unroll
    for (int ni = 0; ni < 4; ni++)
      acc[mi][ni] = (f32x4){0.f, 0.f, 0.f, 0.f};

  const unsigned short* Aseg[3] = {Rhi, Rhi, Rlo};
  const unsigned short* Bseg[3] = {Chi, Clo, Chi};

  for (int seg = 0; seg < 3; seg++) {
    const unsigned short* Ab = Aseg[seg];
    const unsigned short* Bb = Bseg[seg];
    for (int kk = 0; kk < 16; kk++) {
      const int ko = kk * 32;
      #pragma unroll
      for (int c = 0; c < 2; c++) {
        const int ch = w * 2 + c;  // 16-row chunk 0..7
        const unsigned short* ga = Ab + (size_t)(row0 + ch * 16 + srow) * 512 + ko + skq;
        __builtin_amdgcn_global_load_lds(AS1(ga), AS3(&As[ch * 512]), 16, 0, 0);
        const unsigned short* gb = Bb + (size_t)(col0 + ch * 16 + srow) * 512 + ko + skq;
        __builtin_amdgcn_global_load_lds(AS1(gb), AS3(&Bs[ch * 512]), 16, 0, 0);
      }
      __syncthreads();
      bf16x8 a[4], b[4];
      #pragma unroll
      for (int mi = 0; mi < 4; mi++) {
        int r = wr * 64 + mi * 16 + (lane & 15);
        a[mi] = *(const bf16x8*)&As[r * 32 + (lane >> 4) * 8];
      }
      #pragma unroll
      for (int ni = 0; ni < 4; ni++) {
        int r = wc * 64 + ni * 16 + (lane & 15);
        b[ni] = *(const bf16x8*)&Bs[r * 32 + (lane >> 4) * 8];
      }
      #pragma unroll
      for (int mi = 0; mi < 4; mi++)
        #pragma unroll
        for (int ni = 0; ni < 4; ni++)
          acc[mi][ni] = __builtin_amdgcn_mfma_f32_16x16x32_bf16(a[mi], b[ni], acc[mi][ni], 0, 0, 0);
      __syncthreads();
    }
  }

  // epilogue: d2 = cbsq[col] - 2*dot; per-row min over this wave's 64 cols.
  // C/D layout: col = ni*16 + (lane&15), row = mi*16 + (lane>>4)*4 + reg.
  float cq[4];
  #pragma unroll
  for (int ni = 0; ni < 4; ni++)
    cq[ni] = cbsq[col0 + wc * 64 + ni * 16 + (lane & 15)];

  #pragma unroll
  for (int mi = 0; mi < 4; mi++) {
    #pragma unroll
    for (int r = 0; r < 4; r++) {
      unsigned long long m = ~0ull;
      #pragma unroll
      for (int ni = 0; ni < 4; ni++) {
        float d2 = fmaf(-2.f, acc[mi][ni][r], cq[ni]);
        unsigned int col = col0 + wc * 64 + ni * 16 + (lane & 15);
        unsigned long long p = (((unsigned long long)fkey(d2)) << 32) | col;
        if (p < m) m = p;
      }
      #pragma unroll
      for (int off = 1; off < 16; off <<= 1) {
        unsigned long long o = shfl_xor_u64(m, off);
        if (o < m) m = o;
      }
      if ((lane & 15) == 0) {
        int rowg = row0 + wr * 64 + mi * 16 + (lane >> 4) * 4 + r;
        partial[(size_t)rowg * 16 + cb * 2 + wc] = m;
      }
    }
  }
}

// ---------------- reduce 16 partials per row -> index ----------------
__global__ __launch_bounds__(256) void argmin_reduce(
    const unsigned long long* __restrict__ partial, int* __restrict__ ind,
    float* __restrict__ ind_f, int qi) {
  int row = blockIdx.x * 256 + threadIdx.x;
  const unsigned long long* p = partial + (size_t)row * 16;
  unsigned long long m = p[0];
  #pragma unroll
  for (int i = 1; i < 16; i++) {
    unsigned long long v = p[i];
    if (v < m) m = v;
  }
  int c = (int)(m & 0xffffffffu);
  ind[row] = c;
  ind_f[(size_t)row * 8 + qi] = (float)c;
}

// ---------------- rotation trick + residual update: one wave per row ----------------
__global__ __launch_bounds__(256) void rotate_kernel(
    unsigned short* __restrict__ Rhi, unsigned short* __restrict__ Rlo,
    const float* __restrict__ CB, const int* __restrict__ ind,
    float* __restrict__ loss_out, float inv_total, int qi) {
  int wv = threadIdx.x >> 6;
  int lane = threadIdx.x & 63;
  int row = blockIdx.x * 4 + wv;
  size_t base = (size_t)row * 512 + lane * 8;
  ushort8 h = *(const ushort8*)(Rhi + base);
  ushort8 l = *(const ushort8*)(Rlo + base);
  const float* qrow = CB + (size_t)ind[row] * 512 + lane * 8;
  float4 q0 = *(const float4*)qrow;
  float4 q1 = *(const float4*)(qrow + 4);
  float z[8], q[8] = {q0.x, q0.y, q0.z, q0.w, q1.x, q1.y, q1.z, q1.w};
  #pragma unroll
  for (int j = 0; j < 8; j++) z[j] = bf2f(h[j]) + bf2f(l[j]);

  float zz = 0.f, qq = 0.f, zq = 0.f;
  #pragma unroll
  for (int j = 0; j < 8; j++) {
    zz = fmaf(z[j], z[j], zz);
    qq = fmaf(q[j], q[j], qq);
    zq = fmaf(z[j], q[j], zq);
  }
  #pragma unroll
  for (int off = 32; off; off >>= 1) {
    zz += __shfl_xor(zz, off);
    qq += __shfl_xor(qq, off);
    zq += __shfl_xor(zq, off);
  }

  float nz = sqrtf(zz), nq = sqrtf(qq);
  float inz = 1.f / (nz + EPS), inq = 1.f / (nq + EPS);
  float ns  = sqrtf(zz*inz*inz + 2.f*zq*inz*inq + qq*inq*inq);
  float ins = 1.f / ns;
  float zw  = (zz*inz + zq*inq) * ins;   // z . w
  float zzn = zz * inz;                  // z . z_norm
  float scale = nq * inz;                // ||q|| / (||z||+eps)
  float az = scale * (1.f - 2.f * zw * ins * inz);
  float aq = scale * (2.f * zzn - 2.f * zw * ins) * inq;

  #pragma unroll
  for (int j = 0; j < 8; j++) {
    float r = z[j] - (az * z[j] + aq * q[j]);
    unsigned short hh = f2bf(r);
    h[j] = hh;
    l[j] = f2bf(r - bf2f(hh));
  }
  *(ushort8*)(Rhi + base) = h;
  *(ushort8*)(Rlo + base) = l;

  __shared__ float ls[4];
  if (lane == 0) ls[wv] = (zz - 2.f*zq + qq);
  __syncthreads();
  if (threadIdx.x == 0)
    atomicAdd(loss_out + qi, (ls[0] + ls[1] + ls[2] + ls[3]) * inv_total);
}

// ---------------- quantized_out = x - residual_final ----------------
__global__ __launch_bounds__(256) void finish_kernel(const float* __restrict__ x,
                                                     const unsigned short* __restrict__ hi,
                                                     const unsigned short* __restrict__ lo,
                                                     float* __restrict__ qout) {
  size_t i = ((size_t)blockIdx.x * 256 + threadIdx.x) * 8;
  float4 a0 = *(const float4*)(x + i);
  float4 a1 = *(const float4*)(x + i + 4);
  ushort8 h = *(const ushort8*)(hi + i);
  ushort8 l = *(const ushort8*)(lo + i);
  float a[8] = {a0.x, a0.y, a0.z, a0.w, a1.x, a1.y, a1.z, a1.w};
  float4 o0, o1;
  float o[8];
  #pragma unroll
  for (int j = 0; j < 8; j++) o[j] = a[j] - (bf2f(h[j]) + bf2f(l[j]));
  o0 = (float4){o[0], o[1], o[2], o[3]};
  o1 = (float4){o[4], o[5], o[6], o[7]};
  *(float4*)(qout + i) = o0;
  *(float4*)(qout + i + 4) = o1;
}

extern "C" void kernel_launch(void* const* d_in, const int* in_sizes, int n_in,
                              void* d_out, int out_size, void* d_ws, size_t ws_size,
                              hipStream_t stream) {
  const float* x   = (const float*)d_in[0];   // [16, 2048, 512]
  const float* cbs = (const float*)d_in[1];   // [8, 1024, 512]
  float* out = (float*)d_out;
  const size_t M = 32768, D = 512, Q = 8, C = 1024;
  float* qout     = out;                 // [M, D]
  float* idx_out  = out + M * D;         // [M, Q] (as float)
  float* loss_out = idx_out + M * Q;     // [Q]

  // ws layout (bytes):
  // Rhi 32M | Rlo 32M | CBhi 8M | CBlo 8M | partial 4M | cbsq 32K | ind 128K
  unsigned short* Rhi  = (unsigned short*)d_ws;
  unsigned short* Rlo  = Rhi + M * D;
  unsigned short* CBhi = Rlo + M * D;
  unsigned short* CBlo = CBhi + Q * C * D;
  unsigned long long* partial = (unsigned long long*)(CBlo + Q * C * D);
  float* cbsq = (float*)(partial + M * 16);
  int*   ind  = (int*)(cbsq + Q * C);

  hipMemsetAsync(loss_out, 0, Q * sizeof(float), stream);
  split_kernel<<<(int)(M * D / 8 / 256), 256, 0, stream>>>(x, Rhi, Rlo);
  split_kernel<<<(int)(Q * C * D / 8 / 256), 256, 0, stream>>>(cbs, CBhi, CBlo);
  cbsq_kernel<<<(int)((Q * C) / 4), 256, 0, stream>>>(cbs, cbsq);

  const float inv_total = 1.f / (float)(M * D);
  for (int qi = 0; qi < (int)Q; qi++) {
    argmin_mfma<<<dim3(8, 256), 256, 0, stream>>>(
        Rhi, Rlo, CBhi + (size_t)qi * C * D, CBlo + (size_t)qi * C * D,
        cbsq + qi * C, partial);
    argmin_reduce<<<(int)(M / 256), 256, 0, stream>>>(partial, ind, idx_out, qi);
    rotate_kernel<<<(int)(M / 4), 256, 0, stream>>>(
        Rhi, Rlo, cbs + (size_t)qi * C * D, ind, loss_out, inv_total, qi);
  }
  finish_kernel<<<(int)(M * D / 8 / 256), 256, 0, stream>>>(x, Rhi, Rlo, qout);
}

// Round 3
// 1975.901 us; speedup vs baseline: 2.7060x; 1.1897x over previous
//
#include <hip/hip_runtime.h>

#define EPS 1e-6f

typedef __attribute__((ext_vector_type(8))) short bf16x8;
typedef __attribute__((ext_vector_type(4))) float f32x4;
typedef __attribute__((ext_vector_type(8))) unsigned short ushort8;

#define AS1(p) ((const __attribute__((address_space(1))) void*)(p))
#define AS3(p) ((__attribute__((address_space(3))) void*)(p))

__device__ inline unsigned int fkey(float f) {
  unsigned int u = __float_as_uint(f);
  return (u & 0x80000000u) ? ~u : (u | 0x80000000u);
}

__device__ inline unsigned long long shfl_xor_u64(unsigned long long v, int mask) {
  unsigned int lo = (unsigned int)(v & 0xffffffffull);
  unsigned int hi = (unsigned int)(v >> 32);
  lo = (unsigned int)__shfl_xor((int)lo, mask);
  hi = (unsigned int)__shfl_xor((int)hi, mask);
  return (((unsigned long long)hi) << 32) | lo;
}

__device__ inline unsigned short f2bf(float f) {  // RNE fp32 -> bf16
  unsigned int u = __float_as_uint(f);
  u += 0x7fffu + ((u >> 16) & 1u);
  return (unsigned short)(u >> 16);
}
__device__ inline float bf2f(unsigned short h) {
  return __uint_as_float(((unsigned int)h) << 16);
}

// ---------------- codebook squared norms ----------------
__global__ __launch_bounds__(256) void cbsq_kernel(const float* __restrict__ cb,
                                                   float* __restrict__ cbsq) {
  int row = blockIdx.x * 4 + (threadIdx.x >> 6);
  int lane = threadIdx.x & 63;
  const float4* p = (const float4*)(cb + (size_t)row * 512);
  float4 v0 = p[lane];
  float4 v1 = p[lane + 64];
  float s = v0.x*v0.x + v0.y*v0.y + v0.z*v0.z + v0.w*v0.w
          + v1.x*v1.x + v1.y*v1.y + v1.z*v1.z + v1.w*v1.w;
  #pragma unroll
  for (int off = 32; off; off >>= 1) s += __shfl_xor(s, off);
  if (lane == 0) cbsq[row] = s;
}

// ---------------- fp32 -> (hi, lo) bf16 split ----------------
__global__ __launch_bounds__(256) void split_kernel(const float* __restrict__ src,
                                                    unsigned short* __restrict__ hi,
                                                    unsigned short* __restrict__ lo) {
  size_t i = ((size_t)blockIdx.x * 256 + threadIdx.x) * 8;
  float4 v0 = *(const float4*)(src + i);
  float4 v1 = *(const float4*)(src + i + 4);
  float v[8] = {v0.x, v0.y, v0.z, v0.w, v1.x, v1.y, v1.z, v1.w};
  ushort8 h, l;
  #pragma unroll
  for (int j = 0; j < 8; j++) {
    unsigned short hh = f2bf(v[j]);
    h[j] = hh;
    l[j] = f2bf(v[j] - bf2f(hh));
  }
  *(ushort8*)(hi + i) = h;
  *(ushort8*)(lo + i) = l;
}

// ---------------- MFMA distance GEMM + per-block argmin partials ----------------
// Grid (2, 256): blockIdx.x = column half, blockIdx.y = 128-row tile.
// Each block loops over 4 col-tiles of 128 codes; per BK=32 step stages
// A_hi/A_lo/B_hi/B_lo (XOR-swizzled 16-B granules) and fires 48 MFMAs
// (hi*hi + hi*lo + lo*hi). partial[row][cb*2+wc] = packed (ordered_d2, col).
__global__ __launch_bounds__(256, 2) void argmin_mfma(
    const unsigned short* __restrict__ Rhi, const unsigned short* __restrict__ Rlo,
    const unsigned short* __restrict__ Chi, const unsigned short* __restrict__ Clo,
    const float* __restrict__ cbsq, unsigned long long* __restrict__ partial) {
  __shared__ unsigned short As_hi[128 * 32];
  __shared__ unsigned short As_lo[128 * 32];
  __shared__ unsigned short Bs_hi[128 * 32];
  __shared__ unsigned short Bs_lo[128 * 32];
  const int tid = threadIdx.x;
  const int lane = tid & 63;
  const int w = tid >> 6;
  const int wr = w >> 1, wc = w & 1;
  const int bx = blockIdx.x;          // 0..1 column half
  const int row0 = blockIdx.y * 128;

  // staging: lane -> (row-in-chunk rw, LDS slot oq); global octet un-swizzled
  const int rw = lane >> 2, oq = lane & 3;
  const int o_sw = (oq - rw - (rw >> 2)) & 3;
  const size_t goff_base = (size_t)rw * 512 + o_sw * 8;
  // fragment read: lane -> (row m, k-octet g); swizzled slot
  const int m = lane & 15, g = lane >> 4;
  const int f_sw8 = ((g + m + (m >> 2)) & 3) * 8;

  for (int ct = 0; ct < 4; ct++) {
    const int col0 = bx * 512 + ct * 128;
    f32x4 acc[4][4];
    #pragma unroll
    for (int mi = 0; mi < 4; mi++)
      #pragma unroll
      for (int ni = 0; ni < 4; ni++)
        acc[mi][ni] = (f32x4){0.f, 0.f, 0.f, 0.f};

    for (int kk = 0; kk < 16; kk++) {
      const int ko = kk * 32;
      const unsigned short* pAh = Rhi + (size_t)row0 * 512 + ko;
      const unsigned short* pAl = Rlo + (size_t)row0 * 512 + ko;
      const unsigned short* pBh = Chi + (size_t)col0 * 512 + ko;
      const unsigned short* pBl = Clo + (size_t)col0 * 512 + ko;
      #pragma unroll
      for (int c = 0; c < 2; c++) {
        const int ch = w * 2 + c;                 // 16-row chunk 0..7
        const size_t go = (size_t)(ch * 16) * 512 + goff_base;
        const int lb = ch * 512;
        __builtin_amdgcn_global_load_lds(AS1(pAh + go), AS3(&As_hi[lb]), 16, 0, 0);
        __builtin_amdgcn_global_load_lds(AS1(pAl + go), AS3(&As_lo[lb]), 16, 0, 0);
        __builtin_amdgcn_global_load_lds(AS1(pBh + go), AS3(&Bs_hi[lb]), 16, 0, 0);
        __builtin_amdgcn_global_load_lds(AS1(pBl + go), AS3(&Bs_lo[lb]), 16, 0, 0);
      }
      __syncthreads();
      bf16x8 ah[4], al[4], bh[4], bl[4];
      #pragma unroll
      for (int mi = 0; mi < 4; mi++) {
        const int ra = (wr * 64 + mi * 16 + m) * 32 + f_sw8;
        ah[mi] = *(const bf16x8*)&As_hi[ra];
        al[mi] = *(const bf16x8*)&As_lo[ra];
        const int rb = (wc * 64 + mi * 16 + m) * 32 + f_sw8;
        bh[mi] = *(const bf16x8*)&Bs_hi[rb];
        bl[mi] = *(const bf16x8*)&Bs_lo[rb];
      }
      #pragma unroll
      for (int mi = 0; mi < 4; mi++)
        #pragma unroll
        for (int ni = 0; ni < 4; ni++)
          acc[mi][ni] = __builtin_amdgcn_mfma_f32_16x16x32_bf16(ah[mi], bh[ni], acc[mi][ni], 0, 0, 0);
      #pragma unroll
      for (int mi = 0; mi < 4; mi++)
        #pragma unroll
        for (int ni = 0; ni < 4; ni++)
          acc[mi][ni] = __builtin_amdgcn_mfma_f32_16x16x32_bf16(ah[mi], bl[ni], acc[mi][ni], 0, 0, 0);
      #pragma unroll
      for (int mi = 0; mi < 4; mi++)
        #pragma unroll
        for (int ni = 0; ni < 4; ni++)
          acc[mi][ni] = __builtin_amdgcn_mfma_f32_16x16x32_bf16(al[mi], bh[ni], acc[mi][ni], 0, 0, 0);
      __syncthreads();
    }

    // epilogue: d2 = cbsq[col] - 2*dot; per-row min over this wave's 64 cols.
    float cq[4];
    #pragma unroll
    for (int ni = 0; ni < 4; ni++)
      cq[ni] = cbsq[col0 + wc * 64 + ni * 16 + m];

    #pragma unroll
    for (int mi = 0; mi < 4; mi++) {
      #pragma unroll
      for (int r = 0; r < 4; r++) {
        unsigned long long mn = ~0ull;
        #pragma unroll
        for (int ni = 0; ni < 4; ni++) {
          float d2 = fmaf(-2.f, acc[mi][ni][r], cq[ni]);
          unsigned int col = col0 + wc * 64 + ni * 16 + m;
          unsigned long long p = (((unsigned long long)fkey(d2)) << 32) | col;
          if (p < mn) mn = p;
        }
        #pragma unroll
        for (int off = 1; off < 16; off <<= 1) {
          unsigned long long o = shfl_xor_u64(mn, off);
          if (o < mn) mn = o;
        }
        if (m == 0) {
          int rowg = row0 + wr * 64 + mi * 16 + g * 4 + r;
          partial[(size_t)rowg * 16 + (bx * 4 + ct) * 2 + wc] = mn;
        }
      }
    }
  }
}

// ---------------- fused argmin-reduce + rotation + residual update ----------------
__global__ __launch_bounds__(256) void rotate_kernel(
    unsigned short* __restrict__ Rhi, unsigned short* __restrict__ Rlo,
    const float* __restrict__ CB, const unsigned long long* __restrict__ partial,
    float* __restrict__ ind_f, float* __restrict__ loss_out,
    float inv_total, int qi) {
  int wv = threadIdx.x >> 6;
  int lane = threadIdx.x & 63;
  int row = blockIdx.x * 4 + wv;
  unsigned long long mn = partial[(size_t)row * 16 + (lane & 15)];
  #pragma unroll
  for (int off = 1; off < 16; off <<= 1) {
    unsigned long long o = shfl_xor_u64(mn, off);
    if (o < mn) mn = o;
  }
  int c = (int)(mn & 0xffffffffu);
  if (lane == 0) ind_f[(size_t)row * 8 + qi] = (float)c;

  size_t base = (size_t)row * 512 + lane * 8;
  ushort8 h = *(const ushort8*)(Rhi + base);
  ushort8 l = *(const ushort8*)(Rlo + base);
  const float* qrow = CB + (size_t)c * 512 + lane * 8;
  float4 q0 = *(const float4*)qrow;
  float4 q1 = *(const float4*)(qrow + 4);
  float z[8], q[8] = {q0.x, q0.y, q0.z, q0.w, q1.x, q1.y, q1.z, q1.w};
  #pragma unroll
  for (int j = 0; j < 8; j++) z[j] = bf2f(h[j]) + bf2f(l[j]);

  float zz = 0.f, qq = 0.f, zq = 0.f;
  #pragma unroll
  for (int j = 0; j < 8; j++) {
    zz = fmaf(z[j], z[j], zz);
    qq = fmaf(q[j], q[j], qq);
    zq = fmaf(z[j], q[j], zq);
  }
  #pragma unroll
  for (int off = 32; off; off >>= 1) {
    zz += __shfl_xor(zz, off);
    qq += __shfl_xor(qq, off);
    zq += __shfl_xor(zq, off);
  }

  float nz = sqrtf(zz), nq = sqrtf(qq);
  float inz = 1.f / (nz + EPS), inq = 1.f / (nq + EPS);
  float ns  = sqrtf(zz*inz*inz + 2.f*zq*inz*inq + qq*inq*inq);
  float ins = 1.f / ns;
  float zw  = (zz*inz + zq*inq) * ins;
  float zzn = zz * inz;
  float scale = nq * inz;
  float az = scale * (1.f - 2.f * zw * ins * inz);
  float aq = scale * (2.f * zzn - 2.f * zw * ins) * inq;

  #pragma unroll
  for (int j = 0; j < 8; j++) {
    float r = z[j] - (az * z[j] + aq * q[j]);
    unsigned short hh = f2bf(r);
    h[j] = hh;
    l[j] = f2bf(r - bf2f(hh));
  }
  *(ushort8*)(Rhi + base) = h;
  *(ushort8*)(Rlo + base) = l;

  __shared__ float ls[4];
  if (lane == 0) ls[wv] = (zz - 2.f*zq + qq);
  __syncthreads();
  if (threadIdx.x == 0)
    atomicAdd(loss_out + qi, (ls[0] + ls[1] + ls[2] + ls[3]) * inv_total);
}

// ---------------- last stage: rotate fused with qout = x - r_final ----------------
__global__ __launch_bounds__(256) void rotate_finish_kernel(
    const unsigned short* __restrict__ Rhi, const unsigned short* __restrict__ Rlo,
    const float* __restrict__ CB, const unsigned long long* __restrict__ partial,
    float* __restrict__ ind_f, float* __restrict__ loss_out,
    const float* __restrict__ x, float* __restrict__ qout,
    float inv_total, int qi) {
  int wv = threadIdx.x >> 6;
  int lane = threadIdx.x & 63;
  int row = blockIdx.x * 4 + wv;
  unsigned long long mn = partial[(size_t)row * 16 + (lane & 15)];
  #pragma unroll
  for (int off = 1; off < 16; off <<= 1) {
    unsigned long long o = shfl_xor_u64(mn, off);
    if (o < mn) mn = o;
  }
  int c = (int)(mn & 0xffffffffu);
  if (lane == 0) ind_f[(size_t)row * 8 + qi] = (float)c;

  size_t base = (size_t)row * 512 + lane * 8;
  ushort8 h = *(const ushort8*)(Rhi + base);
  ushort8 l = *(const ushort8*)(Rlo + base);
  const float* qrow = CB + (size_t)c * 512 + lane * 8;
  float4 q0 = *(const float4*)qrow;
  float4 q1 = *(const float4*)(qrow + 4);
  float z[8], q[8] = {q0.x, q0.y, q0.z, q0.w, q1.x, q1.y, q1.z, q1.w};
  #pragma unroll
  for (int j = 0; j < 8; j++) z[j] = bf2f(h[j]) + bf2f(l[j]);

  float zz = 0.f, qq = 0.f, zq = 0.f;
  #pragma unroll
  for (int j = 0; j < 8; j++) {
    zz = fmaf(z[j], z[j], zz);
    qq = fmaf(q[j], q[j], qq);
    zq = fmaf(z[j], q[j], zq);
  }
  #pragma unroll
  for (int off = 32; off; off >>= 1) {
    zz += __shfl_xor(zz, off);
    qq += __shfl_xor(qq, off);
    zq += __shfl_xor(zq, off);
  }

  float nz = sqrtf(zz), nq = sqrtf(qq);
  float inz = 1.f / (nz + EPS), inq = 1.f / (nq + EPS);
  float ns  = sqrtf(zz*inz*inz + 2.f*zq*inz*inq + qq*inq*inq);
  float ins = 1.f / ns;
  float zw  = (zz*inz + zq*inq) * ins;
  float zzn = zz * inz;
  float scale = nq * inz;
  float az = scale * (1.f - 2.f * zw * ins * inz);
  float aq = scale * (2.f * zzn - 2.f * zw * ins) * inq;

  float4 x0 = *(const float4*)(x + base);
  float4 x1 = *(const float4*)(x + base + 4);
  float xv[8] = {x0.x, x0.y, x0.z, x0.w, x1.x, x1.y, x1.z, x1.w};
  float o[8];
  #pragma unroll
  for (int j = 0; j < 8; j++) {
    float r = z[j] - (az * z[j] + aq * q[j]);
    o[j] = xv[j] - r;
  }
  *(float4*)(qout + base)     = (float4){o[0], o[1], o[2], o[3]};
  *(float4*)(qout + base + 4) = (float4){o[4], o[5], o[6], o[7]};

  __shared__ float ls[4];
  if (lane == 0) ls[wv] = (zz - 2.f*zq + qq);
  __syncthreads();
  if (threadIdx.x == 0)
    atomicAdd(loss_out + qi, (ls[0] + ls[1] + ls[2] + ls[3]) * inv_total);
}

extern "C" void kernel_launch(void* const* d_in, const int* in_sizes, int n_in,
                              void* d_out, int out_size, void* d_ws, size_t ws_size,
                              hipStream_t stream) {
  const float* x   = (const float*)d_in[0];   // [16, 2048, 512]
  const float* cbs = (const float*)d_in[1];   // [8, 1024, 512]
  float* out = (float*)d_out;
  const size_t M = 32768, D = 512, Q = 8, C = 1024;
  float* qout     = out;                 // [M, D]
  float* idx_out  = out + M * D;         // [M, Q] (as float)
  float* loss_out = idx_out + M * Q;     // [Q]

  // ws: Rhi 32M | Rlo 32M | CBhi 8M | CBlo 8M | partial 4M | cbsq 32K
  unsigned short* Rhi  = (unsigned short*)d_ws;
  unsigned short* Rlo  = Rhi + M * D;
  unsigned short* CBhi = Rlo + M * D;
  unsigned short* CBlo = CBhi + Q * C * D;
  unsigned long long* partial = (unsigned long long*)(CBlo + Q * C * D);
  float* cbsq = (float*)(partial + M * 16);

  hipMemsetAsync(loss_out, 0, Q * sizeof(float), stream);
  split_kernel<<<(int)(M * D / 8 / 256), 256, 0, stream>>>(x, Rhi, Rlo);
  split_kernel<<<(int)(Q * C * D / 8 / 256), 256, 0, stream>>>(cbs, CBhi, CBlo);
  cbsq_kernel<<<(int)((Q * C) / 4), 256, 0, stream>>>(cbs, cbsq);

  const float inv_total = 1.f / (float)(M * D);
  for (int qi = 0; qi < (int)Q; qi++) {
    argmin_mfma<<<dim3(2, 256), 256, 0, stream>>>(
        Rhi, Rlo, CBhi + (size_t)qi * C * D, CBlo + (size_t)qi * C * D,
        cbsq + qi * C, partial);
    if (qi < (int)Q - 1) {
      rotate_kernel<<<(int)(M / 4), 256, 0, stream>>>(
          Rhi, Rlo, cbs + (size_t)qi * C * D, partial, idx_out, loss_out,
          inv_total, qi);
    } else {
      rotate_finish_kernel<<<(int)(M / 4), 256, 0, stream>>>(
          Rhi, Rlo, cbs + (size_t)qi * C * D, partial, idx_out, loss_out,
          x, qout, inv_total, qi);
    }
  }
}

// Round 5
// 1245.603 us; speedup vs baseline: 4.2926x; 1.5863x over previous
//
#include <hip/hip_runtime.h>

#define EPS 1e-6f

typedef __attribute__((ext_vector_type(8))) short bf16x8;
typedef __attribute__((ext_vector_type(4))) float f32x4;
typedef __attribute__((ext_vector_type(8))) unsigned short ushort8;

#define AS1(p) ((const __attribute__((address_space(1))) void*)(p))
#define AS3(p) ((__attribute__((address_space(3))) void*)(p))

__device__ inline unsigned int fkey(float f) {
  unsigned int u = __float_as_uint(f);
  return (u & 0x80000000u) ? ~u : (u | 0x80000000u);
}

__device__ inline unsigned long long shfl_xor_u64(unsigned long long v, int mask) {
  unsigned int lo = (unsigned int)(v & 0xffffffffull);
  unsigned int hi = (unsigned int)(v >> 32);
  lo = (unsigned int)__shfl_xor((int)lo, mask);
  hi = (unsigned int)__shfl_xor((int)hi, mask);
  return (((unsigned long long)hi) << 32) | lo;
}

__device__ inline unsigned short f2bf(float f) {  // RNE fp32 -> bf16
  unsigned int u = __float_as_uint(f);
  u += 0x7fffu + ((u >> 16) & 1u);
  return (unsigned short)(u >> 16);
}
__device__ inline float bf2f(unsigned short h) {
  return __uint_as_float(((unsigned int)h) << 16);
}

// ---------------- prep: splits + codebook norms + loss zero (one kernel) ----------------
__global__ __launch_bounds__(256) void prep_kernel(
    const float* __restrict__ x, const float* __restrict__ cbs,
    unsigned short* __restrict__ Rhi, unsigned short* __restrict__ Rlo,
    unsigned short* __restrict__ CBhi, unsigned short* __restrict__ CBlo,
    float* __restrict__ cbsq, float* __restrict__ loss_out) {
  constexpr size_t M = 32768, D = 512, C = 1024, Q = 8;
  const size_t nthreads = (size_t)gridDim.x * 256;
  const size_t gtid = (size_t)blockIdx.x * 256 + threadIdx.x;
  const int lane = threadIdx.x & 63;
  const int w = threadIdx.x >> 6;

  for (size_t i = gtid; i < M * D / 8; i += nthreads) {
    size_t off = i * 8;
    float4 v0 = *(const float4*)(x + off);
    float4 v1 = *(const float4*)(x + off + 4);
    float v[8] = {v0.x, v0.y, v0.z, v0.w, v1.x, v1.y, v1.z, v1.w};
    ushort8 h, l;
    #pragma unroll
    for (int j = 0; j < 8; j++) {
      unsigned short hh = f2bf(v[j]);
      h[j] = hh;
      l[j] = f2bf(v[j] - bf2f(hh));
    }
    *(ushort8*)(Rhi + off) = h;
    *(ushort8*)(Rlo + off) = l;
  }
  for (size_t i = gtid; i < Q * C * D / 8; i += nthreads) {
    size_t off = i * 8;
    float4 v0 = *(const float4*)(cbs + off);
    float4 v1 = *(const float4*)(cbs + off + 4);
    float v[8] = {v0.x, v0.y, v0.z, v0.w, v1.x, v1.y, v1.z, v1.w};
    ushort8 h, l;
    #pragma unroll
    for (int j = 0; j < 8; j++) {
      unsigned short hh = f2bf(v[j]);
      h[j] = hh;
      l[j] = f2bf(v[j] - bf2f(hh));
    }
    *(ushort8*)(CBhi + off) = h;
    *(ushort8*)(CBlo + off) = l;
  }
  // codebook squared norms (fp32-exact): one wave per row, strided
  for (int row = blockIdx.x * 4 + w; row < (int)(Q * C); row += gridDim.x * 4) {
    const float4* p = (const float4*)(cbs + (size_t)row * 512);
    float4 v0 = p[lane];
    float4 v1 = p[lane + 64];
    float s = v0.x*v0.x + v0.y*v0.y + v0.z*v0.z + v0.w*v0.w
            + v1.x*v1.x + v1.y*v1.y + v1.z*v1.z + v1.w*v1.w;
    #pragma unroll
    for (int off = 32; off; off >>= 1) s += __shfl_xor(s, off);
    if (lane == 0) cbsq[row] = s;
  }
  if (blockIdx.x == 0 && threadIdx.x < (int)Q) loss_out[threadIdx.x] = 0.f;
}

// ---------------- one fused stage: MFMA argmin over ALL 1024 codes + rotate ----------------
// Grid 512, 256 threads (2 blocks/CU). Block owns 64 rows; loops 4 col-tiles
// of 256 codes. Waves 2x2: wave = 32 rows x 128 cols (acc 2x8). Per BK=32 step:
// 48 MFMA (hi*hi + hi*lo + lo*hi), 20 ds_read_b128. Per-row argmin is completed
// block-locally, then the rotation/residual update runs as an epilogue.
__global__ __launch_bounds__(256, 2) void stage_kernel(
    const float* __restrict__ x, const float* __restrict__ cbq_f32,
    unsigned short* __restrict__ Rhi, unsigned short* __restrict__ Rlo,
    const unsigned short* __restrict__ Chi, const unsigned short* __restrict__ Clo,
    const float* __restrict__ cq_base, float* __restrict__ qout,
    float* __restrict__ idx_out, float* __restrict__ loss_out,
    int qi, int last) {
  __shared__ unsigned short As_hi[64 * 32];    // 4 KB
  __shared__ unsigned short As_lo[64 * 32];    // 4 KB
  __shared__ unsigned short Bs_hi[256 * 32];   // 16 KB
  __shared__ unsigned short Bs_lo[256 * 32];   // 16 KB
  __shared__ unsigned long long bestLDS[2][64];
  __shared__ float ls[4];

  const int tid = threadIdx.x;
  const int lane = tid & 63;
  const int w = tid >> 6;
  const int wr = w >> 1, wc = w & 1;
  const int row0 = blockIdx.x * 64;

  // staging: lane -> (row-in-chunk rw, LDS slot oq); global octet un-swizzled
  const int rw = lane >> 2, oq = lane & 3;
  const int o_sw = (oq - rw - (rw >> 2)) & 3;
  // fragment read: lane -> (row m, k-octet g); swizzled slot
  const int m = lane & 15, g = lane >> 4;
  const int f_sw8 = ((g + m + (m >> 2)) & 3) * 8;

  unsigned long long best[2][4];
  #pragma unroll
  for (int mi = 0; mi < 2; mi++)
    #pragma unroll
    for (int r = 0; r < 4; r++) best[mi][r] = ~0ull;

  for (int ct = 0; ct < 4; ct++) {
    const int col0 = ct * 256;
    f32x4 acc[2][8];
    #pragma unroll
    for (int mi = 0; mi < 2; mi++)
      #pragma unroll
      for (int ni = 0; ni < 8; ni++)
        acc[mi][ni] = (f32x4){0.f, 0.f, 0.f, 0.f};

    for (int kk = 0; kk < 16; kk++) {
      const int ko = kk * 32;
      // A: wave w stages chunk w (16 rows)
      {
        const size_t ga = (size_t)(row0 + w * 16 + rw) * 512 + ko + o_sw * 8;
        __builtin_amdgcn_global_load_lds(AS1(Rhi + ga), AS3(&As_hi[w * 512]), 16, 0, 0);
        __builtin_amdgcn_global_load_lds(AS1(Rlo + ga), AS3(&As_lo[w * 512]), 16, 0, 0);
      }
      // B: wave w stages chunks w*4 .. w*4+3 (16 rows each)
      #pragma unroll
      for (int cc = 0; cc < 4; cc++) {
        const int ch = w * 4 + cc;
        const size_t gb = (size_t)(col0 + ch * 16 + rw) * 512 + ko + o_sw * 8;
        __builtin_amdgcn_global_load_lds(AS1(Chi + gb), AS3(&Bs_hi[ch * 512]), 16, 0, 0);
        __builtin_amdgcn_global_load_lds(AS1(Clo + gb), AS3(&Bs_lo[ch * 512]), 16, 0, 0);
      }
      __syncthreads();
      bf16x8 ah[2], al[2], bh[8], bl[8];
      #pragma unroll
      for (int mi = 0; mi < 2; mi++) {
        const int ra = (wr * 32 + mi * 16 + m) * 32 + f_sw8;
        ah[mi] = *(const bf16x8*)&As_hi[ra];
        al[mi] = *(const bf16x8*)&As_lo[ra];
      }
      #pragma unroll
      for (int ni = 0; ni < 8; ni++) {
        const int rb = (wc * 128 + ni * 16 + m) * 32 + f_sw8;
        bh[ni] = *(const bf16x8*)&Bs_hi[rb];
        bl[ni] = *(const bf16x8*)&Bs_lo[rb];
      }
      #pragma unroll
      for (int mi = 0; mi < 2; mi++)
        #pragma unroll
        for (int ni = 0; ni < 8; ni++)
          acc[mi][ni] = __builtin_amdgcn_mfma_f32_16x16x32_bf16(ah[mi], bh[ni], acc[mi][ni], 0, 0, 0);
      #pragma unroll
      for (int mi = 0; mi < 2; mi++)
        #pragma unroll
        for (int ni = 0; ni < 8; ni++)
          acc[mi][ni] = __builtin_amdgcn_mfma_f32_16x16x32_bf16(ah[mi], bl[ni], acc[mi][ni], 0, 0, 0);
      #pragma unroll
      for (int mi = 0; mi < 2; mi++)
        #pragma unroll
        for (int ni = 0; ni < 8; ni++)
          acc[mi][ni] = __builtin_amdgcn_mfma_f32_16x16x32_bf16(al[mi], bh[ni], acc[mi][ni], 0, 0, 0);
      __syncthreads();
    }

    // fold this col-tile into the running per-row argmin
    float cq[8];
    #pragma unroll
    for (int ni = 0; ni < 8; ni++)
      cq[ni] = cq_base[col0 + wc * 128 + ni * 16 + m];

    #pragma unroll
    for (int mi = 0; mi < 2; mi++) {
      #pragma unroll
      for (int r = 0; r < 4; r++) {
        unsigned long long mn = ~0ull;
        #pragma unroll
        for (int ni = 0; ni < 8; ni++) {
          float d2 = fmaf(-2.f, acc[mi][ni][r], cq[ni]);
          unsigned int col = col0 + wc * 128 + ni * 16 + m;
          unsigned long long p = (((unsigned long long)fkey(d2)) << 32) | col;
          if (p < mn) mn = p;
        }
        #pragma unroll
        for (int off = 1; off < 16; off <<= 1) {
          unsigned long long o = shfl_xor_u64(mn, off);
          if (o < mn) mn = o;
        }
        if (mn < best[mi][r]) best[mi][r] = mn;
      }
    }
  }

  // publish per-row argmin halves (wc=0 and wc=1) to LDS
  if (m == 0) {
    #pragma unroll
    for (int mi = 0; mi < 2; mi++)
      #pragma unroll
      for (int r = 0; r < 4; r++)
        bestLDS[wc][wr * 32 + mi * 16 + g * 4 + r] = best[mi][r];
  }
  __syncthreads();

  // ---------------- rotate epilogue: 16 rows per wave ----------------
  float lossacc = 0.f;
  for (int rr = 0; rr < 16; rr++) {
    const int row64 = w * 16 + rr;
    unsigned long long m0 = bestLDS[0][row64], m1 = bestLDS[1][row64];
    unsigned long long mn = m0 < m1 ? m0 : m1;
    const int c = (int)(mn & 0xffffffffu);
    const int row = row0 + row64;
    if (lane == 0) idx_out[(size_t)row * 8 + qi] = (float)c;

    const size_t base = (size_t)row * 512 + lane * 8;
    ushort8 h = *(const ushort8*)(Rhi + base);
    ushort8 l = *(const ushort8*)(Rlo + base);
    const float* qrow = cbq_f32 + (size_t)c * 512 + lane * 8;
    float4 q0 = *(const float4*)qrow;
    float4 q1 = *(const float4*)(qrow + 4);
    float z[8], q[8] = {q0.x, q0.y, q0.z, q0.w, q1.x, q1.y, q1.z, q1.w};
    #pragma unroll
    for (int j = 0; j < 8; j++) z[j] = bf2f(h[j]) + bf2f(l[j]);

    float zz = 0.f, qq = 0.f, zq = 0.f;
    #pragma unroll
    for (int j = 0; j < 8; j++) {
      zz = fmaf(z[j], z[j], zz);
      qq = fmaf(q[j], q[j], qq);
      zq = fmaf(z[j], q[j], zq);
    }
    #pragma unroll
    for (int off = 32; off; off >>= 1) {
      zz += __shfl_xor(zz, off);
      qq += __shfl_xor(qq, off);
      zq += __shfl_xor(zq, off);
    }

    float nz = sqrtf(zz), nq = sqrtf(qq);
    float inz = 1.f / (nz + EPS), inq = 1.f / (nq + EPS);
    float ns  = sqrtf(zz*inz*inz + 2.f*zq*inz*inq + qq*inq*inq);
    float ins = 1.f / ns;
    float zw  = (zz*inz + zq*inq) * ins;
    float zzn = zz * inz;
    float scale = nq * inz;
    float az = scale * (1.f - 2.f * zw * ins * inz);
    float aq = scale * (2.f * zzn - 2.f * zw * ins) * inq;

    if (!last) {
      #pragma unroll
      for (int j = 0; j < 8; j++) {
        float r = z[j] - (az * z[j] + aq * q[j]);
        unsigned short hh = f2bf(r);
        h[j] = hh;
        l[j] = f2bf(r - bf2f(hh));
      }
      *(ushort8*)(Rhi + base) = h;
      *(ushort8*)(Rlo + base) = l;
    } else {
      float4 x0 = *(const float4*)(x + base);
      float4 x1 = *(const float4*)(x + base + 4);
      float xv[8] = {x0.x, x0.y, x0.z, x0.w, x1.x, x1.y, x1.z, x1.w};
      float o[8];
      #pragma unroll
      for (int j = 0; j < 8; j++) {
        float r = z[j] - (az * z[j] + aq * q[j]);
        o[j] = xv[j] - r;
      }
      *(float4*)(qout + base)     = (float4){o[0], o[1], o[2], o[3]};
      *(float4*)(qout + base + 4) = (float4){o[4], o[5], o[6], o[7]};
    }
    lossacc += (zz - 2.f * zq + qq);
  }
  if (lane == 0) ls[w] = lossacc;
  __syncthreads();
  if (tid == 0)
    atomicAdd(loss_out + qi, (ls[0] + ls[1] + ls[2] + ls[3]) *
                             (1.f / (32768.f * 512.f)));
}

extern "C" void kernel_launch(void* const* d_in, const int* in_sizes, int n_in,
                              void* d_out, int out_size, void* d_ws, size_t ws_size,
                              hipStream_t stream) {
  const float* x   = (const float*)d_in[0];   // [16, 2048, 512]
  const float* cbs = (const float*)d_in[1];   // [8, 1024, 512]
  float* out = (float*)d_out;
  const size_t M = 32768, D = 512, Q = 8, C = 1024;
  float* qout     = out;                 // [M, D]
  float* idx_out  = out + M * D;         // [M, Q] (as float)
  float* loss_out = idx_out + M * Q;     // [Q]

  // ws: Rhi 32M | Rlo 32M | CBhi 8M | CBlo 8M | cbsq 32K
  unsigned short* Rhi  = (unsigned short*)d_ws;
  unsigned short* Rlo  = Rhi + M * D;
  unsigned short* CBhi = Rlo + M * D;
  unsigned short* CBlo = CBhi + Q * C * D;
  float* cbsq = (float*)(CBlo + Q * C * D);

  prep_kernel<<<512, 256, 0, stream>>>(x, cbs, Rhi, Rlo, CBhi, CBlo, cbsq, loss_out);

  for (int qi = 0; qi < (int)Q; qi++) {
    stage_kernel<<<512, 256, 0, stream>>>(
        x, cbs + (size_t)qi * C * D, Rhi, Rlo,
        CBhi + (size_t)qi * C * D, CBlo + (size_t)qi * C * D,
        cbsq + qi * C, qout, idx_out, loss_out, qi, qi == (int)Q - 1 ? 1 : 0);
  }
}